// Round 12
// baseline (446.499 us; speedup 1.0000x reference)
//
#include <hip/hip_runtime.h>
#include <stdint.h>
#include <stddef.h>

typedef short bf16x8 __attribute__((ext_vector_type(8)));
typedef float f32x4 __attribute__((ext_vector_type(4)));

__device__ __forceinline__ unsigned short bf16rn(float f){
  unsigned int u = __builtin_bit_cast(unsigned int, f);
  u += 0x7fffu + ((u >> 16) & 1u);
  return (unsigned short)(u >> 16);
}

// global -> LDS direct (16B per lane). dst must be wave-uniform; HW adds lane*16.
__device__ __forceinline__ void gll16(const void* gsrc, void* ldst){
  __builtin_amdgcn_global_load_lds((const __attribute__((address_space(1))) unsigned int*)gsrc,
                                   (__attribute__((address_space(3))) unsigned int*)ldst,
                                   16, 0, 0);
}

__device__ __forceinline__ void barfence(){
  asm volatile("" ::: "memory");
  __builtin_amdgcn_s_barrier();
  asm volatile("" ::: "memory");
}

// ---------------- x fp32 -> bf16 ----------------
__global__ __launch_bounds__(256) void k_cvt_x(const float* __restrict__ x,
                                               unsigned short* __restrict__ xb, long n){
  long i = ((long)blockIdx.x * blockDim.x + threadIdx.x) * 8;
  if (i >= n) return;
  const float4* p = (const float4*)(x + i);
  float4 a = p[0], b = p[1];
  union { unsigned short h[8]; uint4 u; } r;
  r.h[0]=bf16rn(a.x); r.h[1]=bf16rn(a.y); r.h[2]=bf16rn(a.z); r.h[3]=bf16rn(a.w);
  r.h[4]=bf16rn(b.x); r.h[5]=bf16rn(b.y); r.h[6]=bf16rn(b.z); r.h[7]=bf16rn(b.w);
  *(uint4*)(xb + i) = r.u;
}

// ---------------- weight [E][K][N] fp32 -> [E][N][K] bf16 (transpose+convert) ----------------
__global__ __launch_bounds__(256) void k_cvt_w(const float* __restrict__ src,
                                               unsigned short* __restrict__ dst,
                                               int K, int N){
  __shared__ float t[32][33];
  int e = blockIdx.z, k0 = blockIdx.x * 32, n0 = blockIdx.y * 32;
  const float* s = src + (size_t)e * K * N;
  unsigned short* d = dst + (size_t)e * N * K;
  int tx = threadIdx.x, ty = threadIdx.y;
  #pragma unroll
  for (int j = 0; j < 4; j++)
    t[ty + j*8][tx] = s[(size_t)(k0 + ty + j*8) * N + n0 + tx];
  __syncthreads();
  #pragma unroll
  for (int j = 0; j < 4; j++){
    int n = ty + j*8;
    d[(size_t)(n0 + n) * K + k0 + tx] = bf16rn(t[tx][n]);
  }
}

// ---------------- gating: g=relu(x@Wg1+bg1); logits=g@Wg2+bg2; softmax ----------------
__global__ __launch_bounds__(128) void k_gating(const unsigned short* __restrict__ xb,
                                                const unsigned short* __restrict__ wg1t, // [128][1024]
                                                const float* __restrict__ bg1,
                                                const float* __restrict__ wg2,           // [128][16]
                                                const float* __restrict__ bg2,
                                                float* __restrict__ gout, int chunk_base){
  __shared__ unsigned short As[32*64];
  __shared__ unsigned short Bs[128*64];
  __shared__ float gl[32][129];
  __shared__ float redg[32][17];
  const int t = threadIdx.x, wid = t >> 6, l = t & 63;
  const int m0 = blockIdx.x * 32;
  const int jb = l & 7, rsub = l >> 3;
  f32x4 acc[2][4];
  #pragma unroll
  for (int i=0;i<2;i++)
    #pragma unroll
    for (int j=0;j<4;j++) acc[i][j] = (f32x4)0.f;

  for (int kt = 0; kt < 16; kt++){
    int k0 = kt * 64;
    #pragma unroll
    for (int i = 0; i < 2; i++){
      int idx = wid*2 + i; int row = idx*8 + rsub;
      gll16(xb + (size_t)(m0 + row)*1024 + k0 + ((jb ^ (row & 7)) << 3), As + idx*512);
    }
    #pragma unroll
    for (int i = 0; i < 8; i++){
      int idx = wid*8 + i; int row = idx*8 + rsub;
      gll16(wg1t + (size_t)row*1024 + k0 + ((jb ^ (row & 7)) << 3), Bs + idx*512);
    }
    __syncthreads();
    #pragma unroll
    for (int ks = 0; ks < 2; ks++){
      int blk = ks*4 + (l >> 4);
      bf16x8 a[2], b[4];
      #pragma unroll
      for (int fi = 0; fi < 2; fi++){
        int r = fi*16 + (l & 15);
        a[fi] = *(const bf16x8*)(As + r*64 + ((blk ^ (r & 7)) << 3));
      }
      #pragma unroll
      for (int fj = 0; fj < 4; fj++){
        int r = wid*64 + fj*16 + (l & 15);
        b[fj] = *(const bf16x8*)(Bs + r*64 + ((blk ^ (r & 7)) << 3));
      }
      #pragma unroll
      for (int fi = 0; fi < 2; fi++)
        #pragma unroll
        for (int fj = 0; fj < 4; fj++)
          acc[fi][fj] = __builtin_amdgcn_mfma_f32_16x16x32_bf16(a[fi], b[fj], acc[fi][fj], 0, 0, 0);
    }
    __syncthreads();
  }
  #pragma unroll
  for (int fi = 0; fi < 2; fi++)
    #pragma unroll
    for (int fj = 0; fj < 4; fj++){
      int c = wid*64 + fj*16 + (l & 15);
      float bv = bg1[c];
      #pragma unroll
      for (int r = 0; r < 4; r++){
        int row = fi*16 + (l >> 4)*4 + r;
        float v = acc[fi][fj][r] + bv;
        gl[row][c] = v > 0.f ? v : 0.f;
      }
    }
  __syncthreads();

  // parallel logits: thread t handles row = t&31, k-quarter kq = t>>5
  {
    const int row = t & 31, kq = t >> 5;
    float p[16];
    #pragma unroll
    for (int e = 0; e < 16; e++) p[e] = 0.f;
    for (int k = kq*32; k < kq*32 + 32; k++){
      float g = gl[row][k];
      const float* w = wg2 + k*16;
      #pragma unroll
      for (int e = 0; e < 16; e++) p[e] += g * w[e];
    }
    #pragma unroll
    for (int e = 0; e < 16; e++) p[e] += __shfl_xor(p[e], 32);
    if (t >= 64 && t < 96){
      #pragma unroll
      for (int e = 0; e < 16; e++) redg[t - 64][e] = p[e];
    }
    __syncthreads();
    if (t < 32){
      float le[16];
      #pragma unroll
      for (int e = 0; e < 16; e++) le[e] = bg2[e] + p[e] + redg[t][e];
      float m = le[0];
      #pragma unroll
      for (int e = 1; e < 16; e++) m = fmaxf(m, le[e]);
      float s = 0.f;
      #pragma unroll
      for (int e = 0; e < 16; e++){ le[e] = __expf(le[e] - m); s += le[e]; }
      float inv = 1.f / s;
      float4* o = (float4*)(gout + (size_t)(chunk_base + m0 + t)*16);
      #pragma unroll
      for (int q = 0; q < 4; q++)
        o[q] = make_float4(le[4*q]*inv, le[4*q+1]*inv, le[4*q+2]*inv, le[4*q+3]*inv);
    }
  }
}

// ---------------- fused stage1+stage2a: 1-phase read-lag 8-phase schedule ----------------
// Per block: expert e, row tile m0. h = relu(x@W1[e]+b1[e]) (256x256, in LDS),
// out2 = relu(h@W2[e]+b2[e]), outE = out2 . W3[e] + b3[e].
// K-loop (m201-faithful): 8 phases / 2 K-tiles. Phase = {16 MFMA whose operands were
// read in EARLIER phases | 4-8 ds_reads for later phases | 1 half-tile stage |
// [even phases: vmcnt(4)] | ONE barrier}. MFMA never depends on this-phase reads ->
// LDS pipe overlaps matrix pipe; barriers halve vs R6.
// Ledger (stage slots as R6): gates at P2/P4/P6/P8, each vmcnt(4) drains the 2
// halves staged 2 phases earlier: buf1.B0A0 readable P3, buf1.B1A1 P5,
// buf0(t+2).B0A0 P7, buf0.B1A1 P1next. Reads: P1:a1(8) P2:b1(4) P3:b0'(4)
// P4:a0'(8) P5:a1'(8) P6:b1'(4) P7:a0''(8) P8:b0''(4) — all within
// [readable, restage) windows; operand lifetimes tile-disjoint -> single register
// sets (same budget as R6). P7/P8 same-phase reg WAR: MFMA precedes the
// overwriting read in program order.
template<int I0, int J0>
__device__ __forceinline__ void mfma_quad(const bf16x8 (&A)[4][2], const bf16x8 (&Bv)[2][2],
                                          f32x4 (&acc)[8][4]){
  #pragma unroll
  for (int fi = 0; fi < 4; ++fi)
    #pragma unroll
    for (int ks = 0; ks < 2; ++ks){
      acc[I0+fi][J0]   = __builtin_amdgcn_mfma_f32_16x16x32_bf16(A[fi][ks], Bv[0][ks], acc[I0+fi][J0],   0,0,0);
      acc[I0+fi][J0+1] = __builtin_amdgcn_mfma_f32_16x16x32_bf16(A[fi][ks], Bv[1][ks], acc[I0+fi][J0+1], 0,0,0);
    }
}

__global__ __launch_bounds__(512, 2) void k_fused(const unsigned short* __restrict__ xb,
                                                  const unsigned short* __restrict__ w1t,
                                                  const float* __restrict__ b1,
                                                  const unsigned short* __restrict__ w2t, // [E][128][256]
                                                  const float* __restrict__ b2,
                                                  const float* __restrict__ w3,
                                                  const float* __restrict__ b3,
                                                  float* __restrict__ outE,
                                                  int chunkB){
  extern __shared__ __align__(16) char smem[];
  const int t = threadIdx.x;
  const int wid = t >> 6, l = t & 63;
  const int wrow = wid >> 2, wcol = wid & 3;
  const int l3 = l >> 3, l7 = l & 7, l15 = l & 15, l4 = l >> 4;

  // XCD-clustered expert mapping: xcd = bid&7 -> e in {2*xcd, 2*xcd+1}
  const int bid = blockIdx.x;
  const int slot = bid >> 3;
  const int e = (bid & 7)*2 + (slot & 1);
  const int mt = slot >> 1;
  const int m0 = mt * 256, n0 = e * 256;

  // LDS main loop: buf p in {0,1}: [A0,A1,B0,B1] halves of 16 KiB each (128 KiB)
  auto STAGE = [&](int isB, int p, int h, int kt){
    const unsigned short* gb = isB ? (w1t + (size_t)(n0 + h*128) * 1024)
                                   : (xb  + (size_t)(m0 + h*128) * 1024);
    char* dbase = smem + ((p << 16) | (isB << 15) | (h << 14));
    #pragma unroll
    for (int j = 0; j < 2; j++){
      int r = j*64 + wid*8 + l3;
      size_t src = (size_t)r * 1024 + (size_t)kt*64 + (size_t)((l7 ^ (r & 7)) << 3);
      gll16(gb + src, dbase + j*8192 + wid*1024);
    }
  };
  auto LDA = [&](int p, int qm, int fi, int ks) -> bf16x8 {
    int row = qm*64 + fi*16 + l15;
    int kb = (((ks << 2) | l4) ^ (row & 7)) << 4;
    return *(const bf16x8*)(smem + (p << 16) + (wrow << 14) + row*128 + kb);
  };
  auto LDB = [&](int p, int qn, int fj, int ks) -> bf16x8 {
    int row = (wcol & 1)*64 + qn*32 + fj*16 + l15;
    int kb = (((ks << 2) | l4) ^ (row & 7)) << 4;
    return *(const bf16x8*)(smem + (p << 16) + 32768 + ((wcol >> 1) << 14) + row*128 + kb);
  };

  f32x4 acc[8][4];
  #pragma unroll
  for (int i = 0; i < 8; i++)
    #pragma unroll
    for (int j = 0; j < 4; j++) acc[i][j] = (f32x4)0.f;

  bf16x8 a0[4][2], a1[4][2], b0[2][2], b1v[2][2];

  // prologue: tile0 (buf0) all 4 halves, then tile1 (buf1) B0,A0.
  // vmcnt(4) keeps the buf1 pair in flight, drains buf0; barrier; pre-read a0,b0(t0).
  STAGE(1,0,0,0); STAGE(0,0,0,0); STAGE(1,0,1,0); STAGE(0,0,1,0);
  STAGE(1,1,0,1); STAGE(0,1,0,1);
  asm volatile("s_waitcnt vmcnt(4)" ::: "memory");
  barfence();
  #pragma unroll
  for (int fi = 0; fi < 4; ++fi){ a0[fi][0] = LDA(0,0,fi,0); a0[fi][1] = LDA(0,0,fi,1); }
  #pragma unroll
  for (int fj = 0; fj < 2; ++fj){ b0[fj][0] = LDB(0,0,fj,0); b0[fj][1] = LDB(0,0,fj,1); }

  for (int it = 0; it < 8; ++it){
    const int k1 = 2*it + 1;
    int c2 = 2*it + 2, c3 = 2*it + 3;
    if (c2 > 15) c2 = 14;             // tail: identical-data re-stage, same parity/buffer
    if (c3 > 15) c3 = 15;

    // ---- P1: MFMA (a0,b0)(t) | read a1(t) | stage B1->buf1(k1) ----
    STAGE(1,1,1,k1);
    __builtin_amdgcn_s_setprio(1);
    mfma_quad<0,0>(a0, b0, acc);
    __builtin_amdgcn_s_setprio(0);
    #pragma unroll
    for (int fi = 0; fi < 4; ++fi){ a1[fi][0] = LDA(0,1,fi,0); a1[fi][1] = LDA(0,1,fi,1); }
    barfence();

    // ---- P2: MFMA (a1,b0)(t) | read b1(t) | stage A1->buf1(k1) | gate ----
    STAGE(0,1,1,k1);
    __builtin_amdgcn_s_setprio(1);
    mfma_quad<4,0>(a1, b0, acc);
    __builtin_amdgcn_s_setprio(0);
    #pragma unroll
    for (int fj = 0; fj < 2; ++fj){ b1v[fj][0] = LDB(0,1,fj,0); b1v[fj][1] = LDB(0,1,fj,1); }
    asm volatile("s_waitcnt vmcnt(4)" ::: "memory");
    barfence();

    // ---- P3: MFMA (a0,b1)(t) | read b0'(buf1,t+1) | stage B0->buf0(c2) ----
    STAGE(1,0,0,c2);
    __builtin_amdgcn_s_setprio(1);
    mfma_quad<0,2>(a0, b1v, acc);
    __builtin_amdgcn_s_setprio(0);
    #pragma unroll
    for (int fj = 0; fj < 2; ++fj){ b0[fj][0] = LDB(1,0,fj,0); b0[fj][1] = LDB(1,0,fj,1); }
    barfence();

    // ---- P4: MFMA (a1,b1)(t) | read a0'(buf1,t+1) | stage A0->buf0(c2) | gate ----
    STAGE(0,0,0,c2);
    __builtin_amdgcn_s_setprio(1);
    mfma_quad<4,2>(a1, b1v, acc);
    __builtin_amdgcn_s_setprio(0);
    #pragma unroll
    for (int fi = 0; fi < 4; ++fi){ a0[fi][0] = LDA(1,0,fi,0); a0[fi][1] = LDA(1,0,fi,1); }
    asm volatile("s_waitcnt vmcnt(4)" ::: "memory");
    barfence();

    // ---- P5: MFMA (a0',b0')(t+1) | read a1'(buf1,t+1) | stage B1->buf0(c2) ----
    STAGE(1,0,1,c2);
    __builtin_amdgcn_s_setprio(1);
    mfma_quad<0,0>(a0, b0, acc);
    __builtin_amdgcn_s_setprio(0);
    #pragma unroll
    for (int fi = 0; fi < 4; ++fi){ a1[fi][0] = LDA(1,1,fi,0); a1[fi][1] = LDA(1,1,fi,1); }
    barfence();

    // ---- P6: MFMA (a1',b0')(t+1) | read b1'(buf1,t+1) | stage A1->buf0(c2) | gate ----
    STAGE(0,0,1,c2);
    __builtin_amdgcn_s_setprio(1);
    mfma_quad<4,0>(a1, b0, acc);
    __builtin_amdgcn_s_setprio(0);
    #pragma unroll
    for (int fj = 0; fj < 2; ++fj){ b1v[fj][0] = LDB(1,1,fj,0); b1v[fj][1] = LDB(1,1,fj,1); }
    asm volatile("s_waitcnt vmcnt(4)" ::: "memory");
    barfence();

    // ---- P7: MFMA (a0',b1')(t+1) | read a0(buf0,t+2) | stage B0->buf1(c3) ----
    // MFMA precedes the a0-overwriting read (register WAR via program order).
    STAGE(1,1,0,c3);
    __builtin_amdgcn_s_setprio(1);
    mfma_quad<0,2>(a0, b1v, acc);
    __builtin_amdgcn_s_setprio(0);
    #pragma unroll
    for (int fi = 0; fi < 4; ++fi){ a0[fi][0] = LDA(0,0,fi,0); a0[fi][1] = LDA(0,0,fi,1); }
    barfence();

    // ---- P8: MFMA (a1',b1')(t+1) | read b0(buf0,t+2) | stage A0->buf1(c3) | gate ----
    STAGE(0,1,0,c3);
    __builtin_amdgcn_s_setprio(1);
    mfma_quad<4,2>(a1, b1v, acc);
    __builtin_amdgcn_s_setprio(0);
    #pragma unroll
    for (int fj = 0; fj < 2; ++fj){ b0[fj][0] = LDB(0,0,fj,0); b0[fj][1] = LDB(0,0,fj,1); }
    asm volatile("s_waitcnt vmcnt(4)" ::: "memory");
    barfence();
  }

  // ===== fused stage 2 =====
  // drain ALL in-flight gll16 (incl. dead clamped re-stages) before reusing LDS.
  __syncthreads();

  // h[256][256] bf16 at smem[0..128K), row stride 512B, slot-XOR ^(row&31)
  {
    float bv[4];
    #pragma unroll
    for (int fj = 0; fj < 4; ++fj) bv[fj] = b1[e*256 + wcol*64 + fj*16 + l15];
    #pragma unroll
    for (int fi = 0; fi < 8; ++fi)
      #pragma unroll
      for (int fj = 0; fj < 4; ++fj){
        const int col = wcol*64 + fj*16 + l15;
        #pragma unroll
        for (int r = 0; r < 4; ++r){
          const int row = wrow*128 + fi*16 + l4*4 + r;
          float v = acc[fi][fj][r] + bv[fj];
          v = v > 0.f ? v : 0.f;
          *(unsigned short*)(smem + row*512 + ((((col >> 3) ^ (row & 31))) << 4) + ((col & 7) << 1)) = bf16rn(v);
        }
      }
  }

  // W2 chunk staging: [128 n-rows][64 k-cols] bf16 = 16KB, double-buffered at 128K/144K
  const unsigned short* w2e = w2t + (size_t)e*(128*256);
  auto STAGE_W2 = [&](int c, int q){
    char* dbase = smem + 131072 + q*16384;
    #pragma unroll
    for (int j = 0; j < 2; j++){
      int r = j*64 + wid*8 + l3;
      size_t src = (size_t)r*256 + (size_t)c*64 + (size_t)((l7 ^ (r & 7)) << 3);
      gll16(w2e + src, dbase + j*8192 + wid*1024);
    }
  };
  STAGE_W2(0, 0);
  __syncthreads();   // h writes visible + chunk0 landed

  const int wr2 = wid >> 1, wc2 = wid & 1;
  f32x4 acc2[4][4];
  #pragma unroll
  for (int i = 0; i < 4; i++)
    #pragma unroll
    for (int j = 0; j < 4; j++) acc2[i][j] = (f32x4)0.f;

  float w3v[4], b2v[4];
  #pragma unroll
  for (int fj = 0; fj < 4; ++fj){
    int c = wc2*64 + fj*16 + l15;
    w3v[fj] = w3[e*128 + c];
    b2v[fj] = b2[e*128 + c];
  }

  for (int c = 0; c < 4; ++c){
    if (c < 3) STAGE_W2(c+1, (c+1)&1);
    bf16x8 a2[4][2], bb[4][2];
    #pragma unroll
    for (int fi = 0; fi < 4; ++fi)
      #pragma unroll
      for (int ks = 0; ks < 2; ++ks){
        int row = wr2*64 + fi*16 + l15;
        int sl = (c*8 + ks*4 + l4) ^ (row & 31);
        a2[fi][ks] = *(const bf16x8*)(smem + row*512 + (sl << 4));
      }
    #pragma unroll
    for (int fj = 0; fj < 4; ++fj)
      #pragma unroll
      for (int ks = 0; ks < 2; ++ks){
        int n = wc2*64 + fj*16 + l15;
        int sl = (ks*4 + l4) ^ (n & 7);
        bb[fj][ks] = *(const bf16x8*)(smem + 131072 + (c&1)*16384 + n*128 + (sl << 4));
      }
    __builtin_amdgcn_s_setprio(1);
    #pragma unroll
    for (int fi = 0; fi < 4; ++fi)
      #pragma unroll
      for (int fj = 0; fj < 4; ++fj)
        #pragma unroll
        for (int ks = 0; ks < 2; ++ks)
          acc2[fi][fj] = __builtin_amdgcn_mfma_f32_16x16x32_bf16(a2[fi][ks], bb[fj][ks], acc2[fi][fj], 0, 0, 0);
    __builtin_amdgcn_s_setprio(0);
    __syncthreads();   // next chunk landed; reads of wbuf done before overwrite
  }

  // relu(+b2) . w3, 16-lane reduce, cross-wave reduce, write outE
  float* red = (float*)(smem + 131072);
  #pragma unroll
  for (int fi = 0; fi < 4; ++fi)
    #pragma unroll
    for (int r = 0; r < 4; ++r){
      float s = 0.f;
      #pragma unroll
      for (int fj = 0; fj < 4; ++fj){
        float v = acc2[fi][fj][r] + b2v[fj];
        v = v > 0.f ? v : 0.f;
        s += v * w3v[fj];
      }
      s += __shfl_xor(s, 1); s += __shfl_xor(s, 2);
      s += __shfl_xor(s, 4); s += __shfl_xor(s, 8);
      if (l15 == 0){
        int row = wr2*64 + fi*16 + l4*4 + r;
        red[row*2 + wc2] = s;
      }
    }
  __syncthreads();
  if (t < 256)
    outE[(size_t)e*chunkB + m0 + t] = red[t*2 + 0] + red[t*2 + 1] + b3[e];
}

// ---------------- stage2b: final[b] = sum_e g[b,e]*outE[e][b] ----------------
__global__ __launch_bounds__(256) void k_stage2b(const float* __restrict__ outE,
                                                 float* __restrict__ dout,
                                                 int chunk_base, int chunkB, int Btot){
  int row = blockIdx.x*256 + threadIdx.x;
  int rowg = chunk_base + row;
  const float* g = dout + Btot + (size_t)rowg*16;
  float s = 0.f;
  #pragma unroll
  for (int e = 0; e < 16; e++) s += g[e] * outE[(size_t)e*chunkB + row];
  dout[rowg] = s;
}

extern "C" void kernel_launch(void* const* d_in, const int* in_sizes, int n_in,
                              void* d_out, int out_size, void* d_ws, size_t ws_size,
                              hipStream_t stream){
  const float* x   = (const float*)d_in[0];
  const float* W1  = (const float*)d_in[1];
  const float* b1  = (const float*)d_in[2];
  const float* W2  = (const float*)d_in[3];
  const float* b2  = (const float*)d_in[4];
  const float* W3  = (const float*)d_in[5];
  const float* b3  = (const float*)d_in[6];
  const float* Wg1 = (const float*)d_in[7];
  const float* bg1 = (const float*)d_in[8];
  const float* Wg2 = (const float*)d_in[9];
  const float* bg2 = (const float*)d_in[10];
  float* out = (float*)d_out;

  const int B = in_sizes[0] / 1024;   // 32768

  char* ws = (char*)d_ws;
  size_t off = 0;
  auto alloc = [&](size_t bytes){ size_t p = off; off = (off + bytes + 255) & ~(size_t)255; return p; };
  size_t o_w1t  = alloc((size_t)16*256*1024*2);
  size_t o_w2t  = alloc((size_t)16*128*256*2);
  size_t o_wg1t = alloc((size_t)128*1024*2);
  size_t fixed = off;

  // deterministic chunk selection from ws_size (constant across calls)
  // per-row: xb 2048 B + outE 16*4 B = 2112 B
  const int cands[6] = {1, 2, 4, 8, 16, 32};
  int nc = 32;
  for (int i = 0; i < 6; i++){
    size_t cB = (size_t)B / cands[i];
    if (fixed + cB*2112 + 4096 <= ws_size){ nc = cands[i]; break; }
  }
  int chunkB = B / nc;

  size_t o_xb = alloc((size_t)chunkB*1024*2);
  size_t o_oe = alloc((size_t)chunkB*16*4);

  unsigned short* w1t  = (unsigned short*)(ws + o_w1t);
  unsigned short* w2t  = (unsigned short*)(ws + o_w2t);
  unsigned short* wg1t = (unsigned short*)(ws + o_wg1t);
  unsigned short* xb   = (unsigned short*)(ws + o_xb);
  float*          oE   = (float*)(ws + o_oe);

  // allow 160 KiB dynamic LDS for the fused kernel (idempotent, capture-safe)
  hipFuncSetAttribute(reinterpret_cast<const void*>(k_fused),
                      hipFuncAttributeMaxDynamicSharedMemorySize, 163840);

  // weight transpose+convert (once per call)
  k_cvt_w<<<dim3(32, 8, 16), dim3(32, 8), 0, stream>>>(W1, w1t, 1024, 256);
  k_cvt_w<<<dim3(8, 4, 16),  dim3(32, 8), 0, stream>>>(W2, w2t, 256, 128);
  k_cvt_w<<<dim3(32, 4, 1),  dim3(32, 8), 0, stream>>>(Wg1, wg1t, 1024, 128);

  for (int c = 0; c < nc; c++){
    int cb = c * chunkB;
    k_cvt_x<<<chunkB/2, 256, 0, stream>>>(x + (size_t)cb*1024, xb, (long)chunkB*1024);
    k_gating<<<chunkB/32, 128, 0, stream>>>(xb, wg1t, bg1, Wg2, bg2, out + B, cb);
    k_fused<<<chunkB/16, 512, 163840, stream>>>(xb, w1t, b1, w2t, b2, W3, b3, oE, chunkB);
    k_stage2b<<<chunkB/256, 256, 0, stream>>>(oE, out, cb, chunkB, B);
  }
}

// Round 13
// 375.279 us; speedup vs baseline: 1.1898x; 1.1898x over previous
//
#include <hip/hip_runtime.h>
#include <stdint.h>
#include <stddef.h>

typedef short bf16x8 __attribute__((ext_vector_type(8)));
typedef float f32x4 __attribute__((ext_vector_type(4)));

__device__ __forceinline__ unsigned short bf16rn(float f){
  unsigned int u = __builtin_bit_cast(unsigned int, f);
  u += 0x7fffu + ((u >> 16) & 1u);
  return (unsigned short)(u >> 16);
}

// global -> LDS direct (16B per lane). dst must be wave-uniform; HW adds lane*16.
__device__ __forceinline__ void gll16(const void* gsrc, void* ldst){
  __builtin_amdgcn_global_load_lds((const __attribute__((address_space(1))) unsigned int*)gsrc,
                                   (__attribute__((address_space(3))) unsigned int*)ldst,
                                   16, 0, 0);
}

__device__ __forceinline__ void barfence(){
  asm volatile("" ::: "memory");
  __builtin_amdgcn_s_barrier();
  asm volatile("" ::: "memory");
}

// ---------------- weight [E][K][N] fp32 -> [E][N][K] bf16 (transpose+convert) ----------------
__global__ __launch_bounds__(256) void k_cvt_w(const float* __restrict__ src,
                                               unsigned short* __restrict__ dst,
                                               int K, int N){
  __shared__ float t[32][33];
  int e = blockIdx.z, k0 = blockIdx.x * 32, n0 = blockIdx.y * 32;
  const float* s = src + (size_t)e * K * N;
  unsigned short* d = dst + (size_t)e * N * K;
  int tx = threadIdx.x, ty = threadIdx.y;
  #pragma unroll
  for (int j = 0; j < 4; j++)
    t[ty + j*8][tx] = s[(size_t)(k0 + ty + j*8) * N + n0 + tx];
  __syncthreads();
  #pragma unroll
  for (int j = 0; j < 4; j++){
    int n = ty + j*8;
    d[(size_t)(n0 + n) * K + k0 + tx] = bf16rn(t[tx][n]);
  }
}

// ---------------- gating + x-conversion fused ----------------
// Reads x fp32 directly (reg-stage -> bf16 -> swizzled ds_write for own MFMA),
// writes xb (bf16) for k_fused — the standalone cvt_x pass (134 MB re-read) is gone.
// Logits parallel across all 128 threads (4-way k-split + shfl/LDS reduce).
__global__ __launch_bounds__(128) void k_gating(const float* __restrict__ x,
                                                unsigned short* __restrict__ xb,
                                                const unsigned short* __restrict__ wg1t, // [128][1024]
                                                const float* __restrict__ bg1,
                                                const float* __restrict__ wg2,           // [128][16]
                                                const float* __restrict__ bg2,
                                                float* __restrict__ gout, int chunk_base){
  __shared__ unsigned short As[32*64];
  __shared__ unsigned short Bs[128*64];
  __shared__ float gl[32][129];
  __shared__ float redg[32][17];
  const int t = threadIdx.x, wid = t >> 6, l = t & 63;
  const int m0 = blockIdx.x * 32;
  const int jb = l & 7, rsub = l >> 3;
  f32x4 acc[2][4];
  #pragma unroll
  for (int i=0;i<2;i++)
    #pragma unroll
    for (int j=0;j<4;j++) acc[i][j] = (f32x4)0.f;

  for (int kt = 0; kt < 16; kt++){
    int k0 = kt * 64;
    // A-tile: reg-stage x fp32, convert, swizzled LDS write + xb global write.
    // slot s in [0,256): row = s>>3 (0..31), sk = s&7 (8-elem k-slot).
    #pragma unroll
    for (int i = 0; i < 2; i++){
      int s = t + i*128;
      int row = s >> 3, sk = s & 7;
      const float4* px = (const float4*)(x + (size_t)(m0 + row)*1024 + k0 + sk*8);
      float4 u0 = px[0], u1 = px[1];
      union { unsigned short h[8]; uint4 u; bf16x8 v; } r;
      r.h[0]=bf16rn(u0.x); r.h[1]=bf16rn(u0.y); r.h[2]=bf16rn(u0.z); r.h[3]=bf16rn(u0.w);
      r.h[4]=bf16rn(u1.x); r.h[5]=bf16rn(u1.y); r.h[6]=bf16rn(u1.z); r.h[7]=bf16rn(u1.w);
      *(bf16x8*)(As + row*64 + ((sk ^ (row & 7)) << 3)) = r.v;
      *(uint4*)(xb + (size_t)(m0 + row)*1024 + k0 + sk*8) = r.u;
    }
    #pragma unroll
    for (int i = 0; i < 8; i++){
      int idx = wid*8 + i; int row = idx*8 + rsub;
      gll16(wg1t + (size_t)row*1024 + k0 + ((jb ^ (row & 7)) << 3), Bs + idx*512);
    }
    __syncthreads();
    #pragma unroll
    for (int ks = 0; ks < 2; ks++){
      int blk = ks*4 + (l >> 4);
      bf16x8 a[2], b[4];
      #pragma unroll
      for (int fi = 0; fi < 2; fi++){
        int r = fi*16 + (l & 15);
        a[fi] = *(const bf16x8*)(As + r*64 + ((blk ^ (r & 7)) << 3));
      }
      #pragma unroll
      for (int fj = 0; fj < 4; fj++){
        int r = wid*64 + fj*16 + (l & 15);
        b[fj] = *(const bf16x8*)(Bs + r*64 + ((blk ^ (r & 7)) << 3));
      }
      #pragma unroll
      for (int fi = 0; fi < 2; fi++)
        #pragma unroll
        for (int fj = 0; fj < 4; fj++)
          acc[fi][fj] = __builtin_amdgcn_mfma_f32_16x16x32_bf16(a[fi], b[fj], acc[fi][fj], 0, 0, 0);
    }
    __syncthreads();
  }
  #pragma unroll
  for (int fi = 0; fi < 2; fi++)
    #pragma unroll
    for (int fj = 0; fj < 4; fj++){
      int c = wid*64 + fj*16 + (l & 15);
      float bv = bg1[c];
      #pragma unroll
      for (int r = 0; r < 4; r++){
        int row = fi*16 + (l >> 4)*4 + r;
        float v = acc[fi][fj][r] + bv;
        gl[row][c] = v > 0.f ? v : 0.f;
      }
    }
  __syncthreads();

  // parallel logits: thread t handles row = t&31, k-quarter kq = t>>5
  {
    const int row = t & 31, kq = t >> 5;
    float p[16];
    #pragma unroll
    for (int e = 0; e < 16; e++) p[e] = 0.f;
    for (int k = kq*32; k < kq*32 + 32; k++){
      float g = gl[row][k];
      const float* w = wg2 + k*16;
      #pragma unroll
      for (int e = 0; e < 16; e++) p[e] += g * w[e];
    }
    #pragma unroll
    for (int e = 0; e < 16; e++) p[e] += __shfl_xor(p[e], 32);
    if (t >= 64 && t < 96){
      #pragma unroll
      for (int e = 0; e < 16; e++) redg[t - 64][e] = p[e];
    }
    __syncthreads();
    if (t < 32){
      float le[16];
      #pragma unroll
      for (int e = 0; e < 16; e++) le[e] = bg2[e] + p[e] + redg[t][e];
      float m = le[0];
      #pragma unroll
      for (int e = 1; e < 16; e++) m = fmaxf(m, le[e]);
      float s = 0.f;
      #pragma unroll
      for (int e = 0; e < 16; e++){ le[e] = __expf(le[e] - m); s += le[e]; }
      float inv = 1.f / s;
      float4* o = (float4*)(gout + (size_t)(chunk_base + m0 + t)*16);
      #pragma unroll
      for (int q = 0; q < 4; q++)
        o[q] = make_float4(le[4*q]*inv, le[4*q+1]*inv, le[4*q+2]*inv, le[4*q+3]*inv);
    }
  }
}

// ---------------- fused stage1+stage2a (R6 K-loop frozen; stage2 reads W2 from L2) ----------------
// Per block: expert e, row tile m0. h = relu(x@W1[e]+b1[e]) (256x256, kept in LDS),
// out2 = relu(h@W2[e]+b2[e]) (256x128), outE = out2 . W3[e] + b3[e] (256 fp32).
// K-loop swizzle: LDS[row][slot s] = data[row][s ^ (row&7)] (slot = 16B).
// Stage2: h swizzle ^(row&31) (conflict-free, R9-R11); W2 fragments read DIRECTLY
// from global (L2: 2 experts/XCD -> W2[e]=64KB hot) — no LDS staging, no drains.
// Block mapping: XCD x (= bid&7) serves experts {2x, 2x+1} -> W1 L2-resident per XCD.
template<int I0, int J0>
__device__ __forceinline__ void mfma_quad(const bf16x8 (&A)[4][2], const bf16x8 (&Bv)[2][2],
                                          f32x4 (&acc)[8][4]){
  #pragma unroll
  for (int fi = 0; fi < 4; ++fi)
    #pragma unroll
    for (int ks = 0; ks < 2; ++ks){
      acc[I0+fi][J0]   = __builtin_amdgcn_mfma_f32_16x16x32_bf16(A[fi][ks], Bv[0][ks], acc[I0+fi][J0],   0,0,0);
      acc[I0+fi][J0+1] = __builtin_amdgcn_mfma_f32_16x16x32_bf16(A[fi][ks], Bv[1][ks], acc[I0+fi][J0+1], 0,0,0);
    }
}

__global__ __launch_bounds__(512, 2) void k_fused(const unsigned short* __restrict__ xb,
                                                  const unsigned short* __restrict__ w1t,
                                                  const float* __restrict__ b1,
                                                  const unsigned short* __restrict__ w2t, // [E][128][256]
                                                  const float* __restrict__ b2,
                                                  const float* __restrict__ w3,
                                                  const float* __restrict__ b3,
                                                  float* __restrict__ outE,
                                                  int chunkB){
  extern __shared__ __align__(16) char smem[];
  const int t = threadIdx.x;
  const int wid = t >> 6, l = t & 63;
  const int wrow = wid >> 2, wcol = wid & 3;
  const int l3 = l >> 3, l7 = l & 7, l15 = l & 15, l4 = l >> 4;

  // XCD-clustered expert mapping: xcd = bid&7 -> e in {2*xcd, 2*xcd+1}
  const int bid = blockIdx.x;
  const int slot = bid >> 3;
  const int e = (bid & 7)*2 + (slot & 1);
  const int mt = slot >> 1;
  const int m0 = mt * 256, n0 = e * 256;

  // LDS main loop: buf p in {0,1}: [A0,A1,B0,B1] halves of 16 KiB each (128 KiB)
  auto STAGE = [&](int isB, int p, int h, int kt){
    const unsigned short* gb = isB ? (w1t + (size_t)(n0 + h*128) * 1024)
                                   : (xb  + (size_t)(m0 + h*128) * 1024);
    char* dbase = smem + ((p << 16) | (isB << 15) | (h << 14));
    #pragma unroll
    for (int j = 0; j < 2; j++){
      int r = j*64 + wid*8 + l3;
      size_t src = (size_t)r * 1024 + (size_t)kt*64 + (size_t)((l7 ^ (r & 7)) << 3);
      gll16(gb + src, dbase + j*8192 + wid*1024);
    }
  };
  auto LDA = [&](int p, int qm, int fi, int ks) -> bf16x8 {
    int row = qm*64 + fi*16 + l15;
    int kb = (((ks << 2) | l4) ^ (row & 7)) << 4;
    return *(const bf16x8*)(smem + (p << 16) + (wrow << 14) + row*128 + kb);
  };
  auto LDB = [&](int p, int qn, int fj, int ks) -> bf16x8 {
    int row = (wcol & 1)*64 + qn*32 + fj*16 + l15;
    int kb = (((ks << 2) | l4) ^ (row & 7)) << 4;
    return *(const bf16x8*)(smem + (p << 16) + 32768 + ((wcol >> 1) << 14) + row*128 + kb);
  };

  f32x4 acc[8][4];
  #pragma unroll
  for (int i = 0; i < 8; i++)
    #pragma unroll
    for (int j = 0; j < 4; j++) acc[i][j] = (f32x4)0.f;

  bf16x8 a0[4][2], a1[4][2], b0[2][2], b1v[2][2];

  // prologue: tile0 all 4 halves, then tile1 B0,A0
  STAGE(0,0,0,0); STAGE(1,0,0,0); STAGE(0,0,1,0); STAGE(1,0,1,0);
  STAGE(1,1,0,1); STAGE(0,1,0,1);
  asm volatile("s_waitcnt vmcnt(4)" ::: "memory");
  barfence();

  for (int it = 0; it < 8; ++it){
    const int t0 = 2*it, k1 = t0 + 1;
    int c2 = t0 + 2, c3 = t0 + 3;
    if (c2 > 15) c2 = 14;
    if (c3 > 15) c3 = 14;

    // ---- P1 ----
    #pragma unroll
    for (int fi = 0; fi < 4; ++fi){ a0[fi][0] = LDA(0,0,fi,0); a0[fi][1] = LDA(0,0,fi,1); }
    #pragma unroll
    for (int fj = 0; fj < 2; ++fj){ b0[fj][0] = LDB(0,0,fj,0); b0[fj][1] = LDB(0,0,fj,1); }
    STAGE(1,1,1,k1);
    barfence();
    __builtin_amdgcn_s_setprio(1);
    mfma_quad<0,0>(a0, b0, acc);
    __builtin_amdgcn_s_setprio(0);
    barfence();

    // ---- P2 ----
    #pragma unroll
    for (int fj = 0; fj < 2; ++fj){ b1v[fj][0] = LDB(0,1,fj,0); b1v[fj][1] = LDB(0,1,fj,1); }
    STAGE(0,1,1,k1);
    barfence();
    __builtin_amdgcn_s_setprio(1);
    mfma_quad<0,2>(a0, b1v, acc);
    __builtin_amdgcn_s_setprio(0);
    barfence();

    // ---- P3 ----
    #pragma unroll
    for (int fi = 0; fi < 4; ++fi){ a1[fi][0] = LDA(0,1,fi,0); a1[fi][1] = LDA(0,1,fi,1); }
    STAGE(1,0,0,c2);
    barfence();
    __builtin_amdgcn_s_setprio(1);
    mfma_quad<4,2>(a1, b1v, acc);
    __builtin_amdgcn_s_setprio(0);
    barfence();

    // ---- P4 ----
    STAGE(0,0,0,c2);
    barfence();
    __builtin_amdgcn_s_setprio(1);
    mfma_quad<4,0>(a1, b0, acc);
    __builtin_amdgcn_s_setprio(0);
    asm volatile("s_waitcnt vmcnt(4)" ::: "memory");
    barfence();

    // ---- P5 ----
    #pragma unroll
    for (int fi = 0; fi < 4; ++fi){ a0[fi][0] = LDA(1,0,fi,0); a0[fi][1] = LDA(1,0,fi,1); }
    #pragma unroll
    for (int fj = 0; fj < 2; ++fj){ b0[fj][0] = LDB(1,0,fj,0); b0[fj][1] = LDB(1,0,fj,1); }
    STAGE(1,0,1,c2);
    barfence();
    __builtin_amdgcn_s_setprio(1);
    mfma_quad<0,0>(a0, b0, acc);
    __builtin_amdgcn_s_setprio(0);
    barfence();

    // ---- P6 ----
    #pragma unroll
    for (int fj = 0; fj < 2; ++fj){ b1v[fj][0] = LDB(1,1,fj,0); b1v[fj][1] = LDB(1,1,fj,1); }
    STAGE(0,0,1,c2);
    barfence();
    __builtin_amdgcn_s_setprio(1);
    mfma_quad<0,2>(a0, b1v, acc);
    __builtin_amdgcn_s_setprio(0);
    barfence();

    // ---- P7 ----
    #pragma unroll
    for (int fi = 0; fi < 4; ++fi){ a1[fi][0] = LDA(1,1,fi,0); a1[fi][1] = LDA(1,1,fi,1); }
    STAGE(1,1,0,c3);
    barfence();
    __builtin_amdgcn_s_setprio(1);
    mfma_quad<4,2>(a1, b1v, acc);
    __builtin_amdgcn_s_setprio(0);
    barfence();

    // ---- P8 ----
    STAGE(0,1,0,c3);
    barfence();
    __builtin_amdgcn_s_setprio(1);
    mfma_quad<4,0>(a1, b0, acc);
    __builtin_amdgcn_s_setprio(0);
    asm volatile("s_waitcnt vmcnt(4)" ::: "memory");
    barfence();
  }

  // ===== fused stage 2 =====
  // drain ALL in-flight gll16 (incl. dead clamped re-stages) before reusing LDS.
  __syncthreads();

  // h[256][256] bf16 at smem[0..128K), row stride 512B, slot-XOR ^(row&31)
  {
    float bv[4];
    #pragma unroll
    for (int fj = 0; fj < 4; ++fj) bv[fj] = b1[e*256 + wcol*64 + fj*16 + l15];
    #pragma unroll
    for (int fi = 0; fi < 8; ++fi)
      #pragma unroll
      for (int fj = 0; fj < 4; ++fj){
        const int col = wcol*64 + fj*16 + l15;
        #pragma unroll
        for (int r = 0; r < 4; ++r){
          const int row = wrow*128 + fi*16 + l4*4 + r;
          float v = acc[fi][fj][r] + bv[fj];
          v = v > 0.f ? v : 0.f;
          *(unsigned short*)(smem + row*512 + ((((col >> 3) ^ (row & 31))) << 4) + ((col & 7) << 1)) = bf16rn(v);
        }
      }
  }
  __syncthreads();   // h writes visible to all waves

  const unsigned short* w2e = w2t + (size_t)e*(128*256);
  const int wr2 = wid >> 1, wc2 = wid & 1;
  f32x4 acc2[4][4];
  #pragma unroll
  for (int i = 0; i < 4; i++)
    #pragma unroll
    for (int j = 0; j < 4; j++) acc2[i][j] = (f32x4)0.f;

  float w3v[4], b2v[4];
  #pragma unroll
  for (int fj = 0; fj < 4; ++fj){
    int c = wc2*64 + fj*16 + l15;
    w3v[fj] = w3[e*128 + c];
    b2v[fj] = b2[e*128 + c];
  }

  #pragma unroll
  for (int c = 0; c < 4; ++c){
    bf16x8 a2[4][2], bb[4][2];
    #pragma unroll
    for (int fi = 0; fi < 4; ++fi)
      #pragma unroll
      for (int ks = 0; ks < 2; ++ks){
        int row = wr2*64 + fi*16 + l15;
        int sl = (c*8 + ks*4 + l4) ^ (row & 31);
        a2[fi][ks] = *(const bf16x8*)(smem + row*512 + (sl << 4));
      }
    #pragma unroll
    for (int fj = 0; fj < 4; ++fj)
      #pragma unroll
      for (int ks = 0; ks < 2; ++ks){
        int n = wc2*64 + fj*16 + l15;
        bb[fj][ks] = *(const bf16x8*)(w2e + (size_t)n*256 + c*64 + ks*32 + l4*8);
      }
    __builtin_amdgcn_s_setprio(1);
    #pragma unroll
    for (int fi = 0; fi < 4; ++fi)
      #pragma unroll
      for (int fj = 0; fj < 4; ++fj)
        #pragma unroll
        for (int ks = 0; ks < 2; ++ks)
          acc2[fi][fj] = __builtin_amdgcn_mfma_f32_16x16x32_bf16(a2[fi][ks], bb[fj][ks], acc2[fi][fj], 0, 0, 0);
    __builtin_amdgcn_s_setprio(0);
  }

  // relu(+b2) . w3, 16-lane reduce, cross-wave reduce, write outE
  float* red = (float*)(smem + 131072);
  #pragma unroll
  for (int fi = 0; fi < 4; ++fi)
    #pragma unroll
    for (int r = 0; r < 4; ++r){
      float s = 0.f;
      #pragma unroll
      for (int fj = 0; fj < 4; ++fj){
        float v = acc2[fi][fj][r] + b2v[fj];
        v = v > 0.f ? v : 0.f;
        s += v * w3v[fj];
      }
      s += __shfl_xor(s, 1); s += __shfl_xor(s, 2);
      s += __shfl_xor(s, 4); s += __shfl_xor(s, 8);
      if (l15 == 0){
        int row = wr2*64 + fi*16 + l4*4 + r;
        red[row*2 + wc2] = s;
      }
    }
  __syncthreads();
  if (t < 256)
    outE[(size_t)e*chunkB + m0 + t] = red[t*2 + 0] + red[t*2 + 1] + b3[e];
}

// ---------------- stage2b: final[b] = sum_e g[b,e]*outE[e][b] ----------------
__global__ __launch_bounds__(256) void k_stage2b(const float* __restrict__ outE,
                                                 float* __restrict__ dout,
                                                 int chunk_base, int chunkB, int Btot){
  int row = blockIdx.x*256 + threadIdx.x;
  int rowg = chunk_base + row;
  const float* g = dout + Btot + (size_t)rowg*16;
  float s = 0.f;
  #pragma unroll
  for (int e = 0; e < 16; e++) s += g[e] * outE[(size_t)e*chunkB + row];
  dout[rowg] = s;
}

extern "C" void kernel_launch(void* const* d_in, const int* in_sizes, int n_in,
                              void* d_out, int out_size, void* d_ws, size_t ws_size,
                              hipStream_t stream){
  const float* x   = (const float*)d_in[0];
  const float* W1  = (const float*)d_in[1];
  const float* b1  = (const float*)d_in[2];
  const float* W2  = (const float*)d_in[3];
  const float* b2  = (const float*)d_in[4];
  const float* W3  = (const float*)d_in[5];
  const float* b3  = (const float*)d_in[6];
  const float* Wg1 = (const float*)d_in[7];
  const float* bg1 = (const float*)d_in[8];
  const float* Wg2 = (const float*)d_in[9];
  const float* bg2 = (const float*)d_in[10];
  float* out = (float*)d_out;

  const int B = in_sizes[0] / 1024;   // 32768

  char* ws = (char*)d_ws;
  size_t off = 0;
  auto alloc = [&](size_t bytes){ size_t p = off; off = (off + bytes + 255) & ~(size_t)255; return p; };
  size_t o_w1t  = alloc((size_t)16*256*1024*2);
  size_t o_w2t  = alloc((size_t)16*128*256*2);
  size_t o_wg1t = alloc((size_t)128*1024*2);
  size_t fixed = off;

  // deterministic chunk selection from ws_size (constant across calls)
  // per-row: xb 2048 B + outE 16*4 B = 2112 B
  const int cands[6] = {1, 2, 4, 8, 16, 32};
  int nc = 32;
  for (int i = 0; i < 6; i++){
    size_t cB = (size_t)B / cands[i];
    if (fixed + cB*2112 + 4096 <= ws_size){ nc = cands[i]; break; }
  }
  int chunkB = B / nc;

  size_t o_xb = alloc((size_t)chunkB*1024*2);
  size_t o_oe = alloc((size_t)chunkB*16*4);

  unsigned short* w1t  = (unsigned short*)(ws + o_w1t);
  unsigned short* w2t  = (unsigned short*)(ws + o_w2t);
  unsigned short* wg1t = (unsigned short*)(ws + o_wg1t);
  unsigned short* xb   = (unsigned short*)(ws + o_xb);
  float*          oE   = (float*)(ws + o_oe);

  // allow 160 KiB dynamic LDS for the fused kernel (idempotent, capture-safe)
  hipFuncSetAttribute(reinterpret_cast<const void*>(k_fused),
                      hipFuncAttributeMaxDynamicSharedMemorySize, 163840);

  // weight transpose+convert (once per call)
  k_cvt_w<<<dim3(32, 8, 16), dim3(32, 8), 0, stream>>>(W1, w1t, 1024, 256);
  k_cvt_w<<<dim3(8, 4, 16),  dim3(32, 8), 0, stream>>>(W2, w2t, 256, 128);
  k_cvt_w<<<dim3(32, 4, 1),  dim3(32, 8), 0, stream>>>(Wg1, wg1t, 1024, 128);

  for (int c = 0; c < nc; c++){
    int cb = c * chunkB;
    k_gating<<<chunkB/32, 128, 0, stream>>>(x + (size_t)cb*1024, xb, wg1t, bg1, Wg2, bg2, out + B, cb);
    k_fused<<<chunkB/16, 512, 163840, stream>>>(xb, w1t, b1, w2t, b2, W3, b3, oE, chunkB);
    k_stage2b<<<chunkB/256, 256, 0, stream>>>(oE, out, cb, chunkB, B);
  }
}

// Round 14
// 353.555 us; speedup vs baseline: 1.2629x; 1.0614x over previous
//
#include <hip/hip_runtime.h>
#include <stdint.h>
#include <stddef.h>

typedef short bf16x8 __attribute__((ext_vector_type(8)));
typedef float f32x4 __attribute__((ext_vector_type(4)));

__device__ __forceinline__ unsigned short bf16rn(float f){
  unsigned int u = __builtin_bit_cast(unsigned int, f);
  u += 0x7fffu + ((u >> 16) & 1u);
  return (unsigned short)(u >> 16);
}

// global -> LDS direct (16B per lane). dst must be wave-uniform; HW adds lane*16.
__device__ __forceinline__ void gll16(const void* gsrc, void* ldst){
  __builtin_amdgcn_global_load_lds((const __attribute__((address_space(1))) unsigned int*)gsrc,
                                   (__attribute__((address_space(3))) unsigned int*)ldst,
                                   16, 0, 0);
}

__device__ __forceinline__ void barfence(){
  asm volatile("" ::: "memory");
  __builtin_amdgcn_s_barrier();
  asm volatile("" ::: "memory");
}

// ---------------- weight [E][K][N] fp32 -> [E][N][K] bf16 (transpose+convert) ----------------
__global__ __launch_bounds__(256) void k_cvt_w(const float* __restrict__ src,
                                               unsigned short* __restrict__ dst,
                                               int K, int N){
  __shared__ float t[32][33];
  int e = blockIdx.z, k0 = blockIdx.x * 32, n0 = blockIdx.y * 32;
  const float* s = src + (size_t)e * K * N;
  unsigned short* d = dst + (size_t)e * N * K;
  int tx = threadIdx.x, ty = threadIdx.y;
  #pragma unroll
  for (int j = 0; j < 4; j++)
    t[ty + j*8][tx] = s[(size_t)(k0 + ty + j*8) * N + n0 + tx];
  __syncthreads();
  #pragma unroll
  for (int j = 0; j < 4; j++){
    int n = ty + j*8;
    d[(size_t)(n0 + n) * K + k0 + tx] = bf16rn(t[tx][n]);
  }
}

// ---------------- gating + x-conversion fused ----------------
// Reads x fp32 directly (reg-stage -> bf16 -> swizzled ds_write for own MFMA),
// writes xb (bf16) for k_fused — the standalone cvt_x pass (134 MB re-read) is gone.
// Logits parallel across all 128 threads (4-way k-split + shfl/LDS reduce).
__global__ __launch_bounds__(128) void k_gating(const float* __restrict__ x,
                                                unsigned short* __restrict__ xb,
                                                const unsigned short* __restrict__ wg1t, // [128][1024]
                                                const float* __restrict__ bg1,
                                                const float* __restrict__ wg2,           // [128][16]
                                                const float* __restrict__ bg2,
                                                float* __restrict__ gout, int chunk_base){
  __shared__ unsigned short As[32*64];
  __shared__ unsigned short Bs[128*64];
  __shared__ float gl[32][129];
  __shared__ float redg[32][17];
  const int t = threadIdx.x, wid = t >> 6, l = t & 63;
  const int m0 = blockIdx.x * 32;
  const int jb = l & 7, rsub = l >> 3;
  f32x4 acc[2][4];
  #pragma unroll
  for (int i=0;i<2;i++)
    #pragma unroll
    for (int j=0;j<4;j++) acc[i][j] = (f32x4)0.f;

  for (int kt = 0; kt < 16; kt++){
    int k0 = kt * 64;
    // A-tile: reg-stage x fp32, convert, swizzled LDS write + xb global write.
    #pragma unroll
    for (int i = 0; i < 2; i++){
      int s = t + i*128;
      int row = s >> 3, sk = s & 7;
      const float4* px = (const float4*)(x + (size_t)(m0 + row)*1024 + k0 + sk*8);
      float4 u0 = px[0], u1 = px[1];
      union { unsigned short h[8]; uint4 u; bf16x8 v; } r;
      r.h[0]=bf16rn(u0.x); r.h[1]=bf16rn(u0.y); r.h[2]=bf16rn(u0.z); r.h[3]=bf16rn(u0.w);
      r.h[4]=bf16rn(u1.x); r.h[5]=bf16rn(u1.y); r.h[6]=bf16rn(u1.z); r.h[7]=bf16rn(u1.w);
      *(bf16x8*)(As + row*64 + ((sk ^ (row & 7)) << 3)) = r.v;
      *(uint4*)(xb + (size_t)(m0 + row)*1024 + k0 + sk*8) = r.u;
    }
    #pragma unroll
    for (int i = 0; i < 8; i++){
      int idx = wid*8 + i; int row = idx*8 + rsub;
      gll16(wg1t + (size_t)row*1024 + k0 + ((jb ^ (row & 7)) << 3), Bs + idx*512);
    }
    __syncthreads();
    #pragma unroll
    for (int ks = 0; ks < 2; ks++){
      int blk = ks*4 + (l >> 4);
      bf16x8 a[2], b[4];
      #pragma unroll
      for (int fi = 0; fi < 2; fi++){
        int r = fi*16 + (l & 15);
        a[fi] = *(const bf16x8*)(As + r*64 + ((blk ^ (r & 7)) << 3));
      }
      #pragma unroll
      for (int fj = 0; fj < 4; fj++){
        int r = wid*64 + fj*16 + (l & 15);
        b[fj] = *(const bf16x8*)(Bs + r*64 + ((blk ^ (r & 7)) << 3));
      }
      #pragma unroll
      for (int fi = 0; fi < 2; fi++)
        #pragma unroll
        for (int fj = 0; fj < 4; fj++)
          acc[fi][fj] = __builtin_amdgcn_mfma_f32_16x16x32_bf16(a[fi], b[fj], acc[fi][fj], 0, 0, 0);
    }
    __syncthreads();
  }
  #pragma unroll
  for (int fi = 0; fi < 2; fi++)
    #pragma unroll
    for (int fj = 0; fj < 4; fj++){
      int c = wid*64 + fj*16 + (l & 15);
      float bv = bg1[c];
      #pragma unroll
      for (int r = 0; r < 4; r++){
        int row = fi*16 + (l >> 4)*4 + r;
        float v = acc[fi][fj][r] + bv;
        gl[row][c] = v > 0.f ? v : 0.f;
      }
    }
  __syncthreads();

  // parallel logits: thread t handles row = t&31, k-quarter kq = t>>5
  {
    const int row = t & 31, kq = t >> 5;
    float p[16];
    #pragma unroll
    for (int e = 0; e < 16; e++) p[e] = 0.f;
    for (int k = kq*32; k < kq*32 + 32; k++){
      float g = gl[row][k];
      const float* w = wg2 + k*16;
      #pragma unroll
      for (int e = 0; e < 16; e++) p[e] += g * w[e];
    }
    #pragma unroll
    for (int e = 0; e < 16; e++) p[e] += __shfl_xor(p[e], 32);
    if (t >= 64 && t < 96){
      #pragma unroll
      for (int e = 0; e < 16; e++) redg[t - 64][e] = p[e];
    }
    __syncthreads();
    if (t < 32){
      float le[16];
      #pragma unroll
      for (int e = 0; e < 16; e++) le[e] = bg2[e] + p[e] + redg[t][e];
      float m = le[0];
      #pragma unroll
      for (int e = 1; e < 16; e++) m = fmaxf(m, le[e]);
      float s = 0.f;
      #pragma unroll
      for (int e = 0; e < 16; e++){ le[e] = __expf(le[e] - m); s += le[e]; }
      float inv = 1.f / s;
      float4* o = (float4*)(gout + (size_t)(chunk_base + m0 + t)*16);
      #pragma unroll
      for (int q = 0; q < 4; q++)
        o[q] = make_float4(le[4*q]*inv, le[4*q+1]*inv, le[4*q+2]*inv, le[4*q+3]*inv);
    }
  }
}

// ---------------- fused stage1+stage2a (R6 K-loop + LDS-staged W2, both verified-best) ----------------
// Per block: expert e, row tile m0. h = relu(x@W1[e]+b1[e]) (256x256, kept in LDS),
// out2 = relu(h@W2[e]+b2[e]) (256x128), outE = out2 . W3[e] + b3[e] (256 fp32).
// K-loop swizzle: LDS[row][slot s] = data[row][s ^ (row&7)] (slot = 16B).
// Stage2: h swizzle ^(row&31) (conflict-free, R9-R11); W2 staged via gll16 into
// double-buffered 16KB chunks (R13 showed direct-L2 reads cost +30us vs this).
// Block mapping: XCD x (= bid&7) serves experts {2x, 2x+1} -> W1 L2-resident per XCD.
template<int I0, int J0>
__device__ __forceinline__ void mfma_quad(const bf16x8 (&A)[4][2], const bf16x8 (&Bv)[2][2],
                                          f32x4 (&acc)[8][4]){
  #pragma unroll
  for (int fi = 0; fi < 4; ++fi)
    #pragma unroll
    for (int ks = 0; ks < 2; ++ks){
      acc[I0+fi][J0]   = __builtin_amdgcn_mfma_f32_16x16x32_bf16(A[fi][ks], Bv[0][ks], acc[I0+fi][J0],   0,0,0);
      acc[I0+fi][J0+1] = __builtin_amdgcn_mfma_f32_16x16x32_bf16(A[fi][ks], Bv[1][ks], acc[I0+fi][J0+1], 0,0,0);
    }
}

__global__ __launch_bounds__(512, 2) void k_fused(const unsigned short* __restrict__ xb,
                                                  const unsigned short* __restrict__ w1t,
                                                  const float* __restrict__ b1,
                                                  const unsigned short* __restrict__ w2t, // [E][128][256]
                                                  const float* __restrict__ b2,
                                                  const float* __restrict__ w3,
                                                  const float* __restrict__ b3,
                                                  float* __restrict__ outE,
                                                  int chunkB){
  extern __shared__ __align__(16) char smem[];
  const int t = threadIdx.x;
  const int wid = t >> 6, l = t & 63;
  const int wrow = wid >> 2, wcol = wid & 3;
  const int l3 = l >> 3, l7 = l & 7, l15 = l & 15, l4 = l >> 4;

  // XCD-clustered expert mapping: xcd = bid&7 -> e in {2*xcd, 2*xcd+1}
  const int bid = blockIdx.x;
  const int slot = bid >> 3;
  const int e = (bid & 7)*2 + (slot & 1);
  const int mt = slot >> 1;
  const int m0 = mt * 256, n0 = e * 256;

  // LDS main loop: buf p in {0,1}: [A0,A1,B0,B1] halves of 16 KiB each (128 KiB)
  auto STAGE = [&](int isB, int p, int h, int kt){
    const unsigned short* gb = isB ? (w1t + (size_t)(n0 + h*128) * 1024)
                                   : (xb  + (size_t)(m0 + h*128) * 1024);
    char* dbase = smem + ((p << 16) | (isB << 15) | (h << 14));
    #pragma unroll
    for (int j = 0; j < 2; j++){
      int r = j*64 + wid*8 + l3;
      size_t src = (size_t)r * 1024 + (size_t)kt*64 + (size_t)((l7 ^ (r & 7)) << 3);
      gll16(gb + src, dbase + j*8192 + wid*1024);
    }
  };
  auto LDA = [&](int p, int qm, int fi, int ks) -> bf16x8 {
    int row = qm*64 + fi*16 + l15;
    int kb = (((ks << 2) | l4) ^ (row & 7)) << 4;
    return *(const bf16x8*)(smem + (p << 16) + (wrow << 14) + row*128 + kb);
  };
  auto LDB = [&](int p, int qn, int fj, int ks) -> bf16x8 {
    int row = (wcol & 1)*64 + qn*32 + fj*16 + l15;
    int kb = (((ks << 2) | l4) ^ (row & 7)) << 4;
    return *(const bf16x8*)(smem + (p << 16) + 32768 + ((wcol >> 1) << 14) + row*128 + kb);
  };

  f32x4 acc[8][4];
  #pragma unroll
  for (int i = 0; i < 8; i++)
    #pragma unroll
    for (int j = 0; j < 4; j++) acc[i][j] = (f32x4)0.f;

  bf16x8 a0[4][2], a1[4][2], b0[2][2], b1v[2][2];

  // prologue: tile0 all 4 halves, then tile1 B0,A0
  STAGE(0,0,0,0); STAGE(1,0,0,0); STAGE(0,0,1,0); STAGE(1,0,1,0);
  STAGE(1,1,0,1); STAGE(0,1,0,1);
  asm volatile("s_waitcnt vmcnt(4)" ::: "memory");
  barfence();

  for (int it = 0; it < 8; ++it){
    const int t0 = 2*it, k1 = t0 + 1;
    int c2 = t0 + 2, c3 = t0 + 3;
    if (c2 > 15) c2 = 14;
    if (c3 > 15) c3 = 14;

    // ---- P1 ----
    #pragma unroll
    for (int fi = 0; fi < 4; ++fi){ a0[fi][0] = LDA(0,0,fi,0); a0[fi][1] = LDA(0,0,fi,1); }
    #pragma unroll
    for (int fj = 0; fj < 2; ++fj){ b0[fj][0] = LDB(0,0,fj,0); b0[fj][1] = LDB(0,0,fj,1); }
    STAGE(1,1,1,k1);
    barfence();
    __builtin_amdgcn_s_setprio(1);
    mfma_quad<0,0>(a0, b0, acc);
    __builtin_amdgcn_s_setprio(0);
    barfence();

    // ---- P2 ----
    #pragma unroll
    for (int fj = 0; fj < 2; ++fj){ b1v[fj][0] = LDB(0,1,fj,0); b1v[fj][1] = LDB(0,1,fj,1); }
    STAGE(0,1,1,k1);
    barfence();
    __builtin_amdgcn_s_setprio(1);
    mfma_quad<0,2>(a0, b1v, acc);
    __builtin_amdgcn_s_setprio(0);
    barfence();

    // ---- P3 ----
    #pragma unroll
    for (int fi = 0; fi < 4; ++fi){ a1[fi][0] = LDA(0,1,fi,0); a1[fi][1] = LDA(0,1,fi,1); }
    STAGE(1,0,0,c2);
    barfence();
    __builtin_amdgcn_s_setprio(1);
    mfma_quad<4,2>(a1, b1v, acc);
    __builtin_amdgcn_s_setprio(0);
    barfence();

    // ---- P4 ----
    STAGE(0,0,0,c2);
    barfence();
    __builtin_amdgcn_s_setprio(1);
    mfma_quad<4,0>(a1, b0, acc);
    __builtin_amdgcn_s_setprio(0);
    asm volatile("s_waitcnt vmcnt(4)" ::: "memory");
    barfence();

    // ---- P5 ----
    #pragma unroll
    for (int fi = 0; fi < 4; ++fi){ a0[fi][0] = LDA(1,0,fi,0); a0[fi][1] = LDA(1,0,fi,1); }
    #pragma unroll
    for (int fj = 0; fj < 2; ++fj){ b0[fj][0] = LDB(1,0,fj,0); b0[fj][1] = LDB(1,0,fj,1); }
    STAGE(1,0,1,c2);
    barfence();
    __builtin_amdgcn_s_setprio(1);
    mfma_quad<0,0>(a0, b0, acc);
    __builtin_amdgcn_s_setprio(0);
    barfence();

    // ---- P6 ----
    #pragma unroll
    for (int fj = 0; fj < 2; ++fj){ b1v[fj][0] = LDB(1,1,fj,0); b1v[fj][1] = LDB(1,1,fj,1); }
    STAGE(0,0,1,c2);
    barfence();
    __builtin_amdgcn_s_setprio(1);
    mfma_quad<0,2>(a0, b1v, acc);
    __builtin_amdgcn_s_setprio(0);
    barfence();

    // ---- P7 ----
    #pragma unroll
    for (int fi = 0; fi < 4; ++fi){ a1[fi][0] = LDA(1,1,fi,0); a1[fi][1] = LDA(1,1,fi,1); }
    STAGE(1,1,0,c3);
    barfence();
    __builtin_amdgcn_s_setprio(1);
    mfma_quad<4,2>(a1, b1v, acc);
    __builtin_amdgcn_s_setprio(0);
    barfence();

    // ---- P8 ----
    STAGE(0,1,0,c3);
    barfence();
    __builtin_amdgcn_s_setprio(1);
    mfma_quad<4,0>(a1, b0, acc);
    __builtin_amdgcn_s_setprio(0);
    asm volatile("s_waitcnt vmcnt(4)" ::: "memory");
    barfence();
  }

  // ===== fused stage 2 =====
  // drain ALL in-flight gll16 (incl. dead clamped re-stages) before reusing LDS.
  __syncthreads();

  // h[256][256] bf16 at smem[0..128K), row stride 512B, slot-XOR ^(row&31)
  {
    float bv[4];
    #pragma unroll
    for (int fj = 0; fj < 4; ++fj) bv[fj] = b1[e*256 + wcol*64 + fj*16 + l15];
    #pragma unroll
    for (int fi = 0; fi < 8; ++fi)
      #pragma unroll
      for (int fj = 0; fj < 4; ++fj){
        const int col = wcol*64 + fj*16 + l15;
        #pragma unroll
        for (int r = 0; r < 4; ++r){
          const int row = wrow*128 + fi*16 + l4*4 + r;
          float v = acc[fi][fj][r] + bv[fj];
          v = v > 0.f ? v : 0.f;
          *(unsigned short*)(smem + row*512 + ((((col >> 3) ^ (row & 31))) << 4) + ((col & 7) << 1)) = bf16rn(v);
        }
      }
  }

  // W2 chunk staging: [128 n-rows][64 k-cols] bf16 = 16KB, double-buffered at 128K/144K
  const unsigned short* w2e = w2t + (size_t)e*(128*256);
  auto STAGE_W2 = [&](int c, int q){
    char* dbase = smem + 131072 + q*16384;
    #pragma unroll
    for (int j = 0; j < 2; j++){
      int r = j*64 + wid*8 + l3;
      size_t src = (size_t)r*256 + (size_t)c*64 + (size_t)((l7 ^ (r & 7)) << 3);
      gll16(w2e + src, dbase + j*8192 + wid*1024);
    }
  };
  STAGE_W2(0, 0);
  __syncthreads();   // h writes visible + chunk0 landed

  const int wr2 = wid >> 1, wc2 = wid & 1;
  f32x4 acc2[4][4];
  #pragma unroll
  for (int i = 0; i < 4; i++)
    #pragma unroll
    for (int j = 0; j < 4; j++) acc2[i][j] = (f32x4)0.f;

  float w3v[4], b2v[4];
  #pragma unroll
  for (int fj = 0; fj < 4; ++fj){
    int c = wc2*64 + fj*16 + l15;
    w3v[fj] = w3[e*128 + c];
    b2v[fj] = b2[e*128 + c];
  }

  for (int c = 0; c < 4; ++c){
    if (c < 3) STAGE_W2(c+1, (c+1)&1);
    bf16x8 a2[4][2], bb[4][2];
    #pragma unroll
    for (int fi = 0; fi < 4; ++fi)
      #pragma unroll
      for (int ks = 0; ks < 2; ++ks){
        int row = wr2*64 + fi*16 + l15;
        int sl = (c*8 + ks*4 + l4) ^ (row & 31);
        a2[fi][ks] = *(const bf16x8*)(smem + row*512 + (sl << 4));
      }
    #pragma unroll
    for (int fj = 0; fj < 4; ++fj)
      #pragma unroll
      for (int ks = 0; ks < 2; ++ks){
        int n = wc2*64 + fj*16 + l15;
        int sl = (ks*4 + l4) ^ (n & 7);
        bb[fj][ks] = *(const bf16x8*)(smem + 131072 + (c&1)*16384 + n*128 + (sl << 4));
      }
    __builtin_amdgcn_s_setprio(1);
    #pragma unroll
    for (int fi = 0; fi < 4; ++fi)
      #pragma unroll
      for (int fj = 0; fj < 4; ++fj)
        #pragma unroll
        for (int ks = 0; ks < 2; ++ks)
          acc2[fi][fj] = __builtin_amdgcn_mfma_f32_16x16x32_bf16(a2[fi][ks], bb[fj][ks], acc2[fi][fj], 0, 0, 0);
    __builtin_amdgcn_s_setprio(0);
    __syncthreads();   // next chunk landed; reads of wbuf done before overwrite
  }

  // relu(+b2) . w3, 16-lane reduce, cross-wave reduce, write outE
  float* red = (float*)(smem + 131072);
  #pragma unroll
  for (int fi = 0; fi < 4; ++fi)
    #pragma unroll
    for (int r = 0; r < 4; ++r){
      float s = 0.f;
      #pragma unroll
      for (int fj = 0; fj < 4; ++fj){
        float v = acc2[fi][fj][r] + b2v[fj];
        v = v > 0.f ? v : 0.f;
        s += v * w3v[fj];
      }
      s += __shfl_xor(s, 1); s += __shfl_xor(s, 2);
      s += __shfl_xor(s, 4); s += __shfl_xor(s, 8);
      if (l15 == 0){
        int row = wr2*64 + fi*16 + l4*4 + r;
        red[row*2 + wc2] = s;
      }
    }
  __syncthreads();
  if (t < 256)
    outE[(size_t)e*chunkB + m0 + t] = red[t*2 + 0] + red[t*2 + 1] + b3[e];
}

// ---------------- stage2b: final[b] = sum_e g[b,e]*outE[e][b] ----------------
__global__ __launch_bounds__(256) void k_stage2b(const float* __restrict__ outE,
                                                 float* __restrict__ dout,
                                                 int chunk_base, int chunkB, int Btot){
  int row = blockIdx.x*256 + threadIdx.x;
  int rowg = chunk_base + row;
  const float* g = dout + Btot + (size_t)rowg*16;
  float s = 0.f;
  #pragma unroll
  for (int e = 0; e < 16; e++) s += g[e] * outE[(size_t)e*chunkB + row];
  dout[rowg] = s;
}

extern "C" void kernel_launch(void* const* d_in, const int* in_sizes, int n_in,
                              void* d_out, int out_size, void* d_ws, size_t ws_size,
                              hipStream_t stream){
  const float* x   = (const float*)d_in[0];
  const float* W1  = (const float*)d_in[1];
  const float* b1  = (const float*)d_in[2];
  const float* W2  = (const float*)d_in[3];
  const float* b2  = (const float*)d_in[4];
  const float* W3  = (const float*)d_in[5];
  const float* b3  = (const float*)d_in[6];
  const float* Wg1 = (const float*)d_in[7];
  const float* bg1 = (const float*)d_in[8];
  const float* Wg2 = (const float*)d_in[9];
  const float* bg2 = (const float*)d_in[10];
  float* out = (float*)d_out;

  const int B = in_sizes[0] / 1024;   // 32768

  char* ws = (char*)d_ws;
  size_t off = 0;
  auto alloc = [&](size_t bytes){ size_t p = off; off = (off + bytes + 255) & ~(size_t)255; return p; };
  size_t o_w1t  = alloc((size_t)16*256*1024*2);
  size_t o_w2t  = alloc((size_t)16*128*256*2);
  size_t o_wg1t = alloc((size_t)128*1024*2);
  size_t fixed = off;

  // deterministic chunk selection from ws_size (constant across calls)
  // per-row: xb 2048 B + outE 16*4 B = 2112 B
  const int cands[6] = {1, 2, 4, 8, 16, 32};
  int nc = 32;
  for (int i = 0; i < 6; i++){
    size_t cB = (size_t)B / cands[i];
    if (fixed + cB*2112 + 4096 <= ws_size){ nc = cands[i]; break; }
  }
  int chunkB = B / nc;

  size_t o_xb = alloc((size_t)chunkB*1024*2);
  size_t o_oe = alloc((size_t)chunkB*16*4);

  unsigned short* w1t  = (unsigned short*)(ws + o_w1t);
  unsigned short* w2t  = (unsigned short*)(ws + o_w2t);
  unsigned short* wg1t = (unsigned short*)(ws + o_wg1t);
  unsigned short* xb   = (unsigned short*)(ws + o_xb);
  float*          oE   = (float*)(ws + o_oe);

  // allow 160 KiB dynamic LDS for the fused kernel (idempotent, capture-safe)
  hipFuncSetAttribute(reinterpret_cast<const void*>(k_fused),
                      hipFuncAttributeMaxDynamicSharedMemorySize, 163840);

  // weight transpose+convert (once per call)
  k_cvt_w<<<dim3(32, 8, 16), dim3(32, 8), 0, stream>>>(W1, w1t, 1024, 256);
  k_cvt_w<<<dim3(8, 4, 16),  dim3(32, 8), 0, stream>>>(W2, w2t, 256, 128);
  k_cvt_w<<<dim3(32, 4, 1),  dim3(32, 8), 0, stream>>>(Wg1, wg1t, 1024, 128);

  for (int c = 0; c < nc; c++){
    int cb = c * chunkB;
    k_gating<<<chunkB/32, 128, 0, stream>>>(x + (size_t)cb*1024, xb, wg1t, bg1, Wg2, bg2, out + B, cb);
    k_fused<<<chunkB/16, 512, 163840, stream>>>(xb, w1t, b1, w2t, b2, W3, b3, oE, chunkB);
    k_stage2b<<<chunkB/256, 256, 0, stream>>>(oE, out, cb, chunkB, B);
  }
}